// Round 9
// baseline (31.330 us; speedup 1.0000x reference)
//
#include <hip/hip_runtime.h>

#define DIM 7
#define HD  32   // hidden width
#define P2  21   // C(7,2)
#define P3  35   // C(7,3)
#define BLK 256
#define NT  3    // 16-wide output-col tiles (48 cols, 35 used)
#define TPW 2    // 16-row tiles per wave
#define WPB (BLK / 64)
#define WSLAB (TPW * 16 * DIM)   // 224 floats of x per wave
#define MSTR 40                  // Mh row stride (f16) — depads b128 bank conflicts

typedef __attribute__((ext_vector_type(8))) _Float16 half8v;  // MFMA A/B operand
typedef __attribute__((ext_vector_type(4))) float  float4v;   // MFMA accumulator
typedef __attribute__((ext_vector_type(2))) float  float2v;

// packed (i | j<<8 | k<<16) for lexicographic triples of 7
static __device__ const unsigned TRIP[P3] = {
  0x020100,0x030100,0x040100,0x050100,0x060100,
  0x030200,0x040200,0x050200,0x060200,
  0x040300,0x050300,0x060300,
  0x050400,0x060400,
  0x060500,
  0x030201,0x040201,0x050201,0x060201,
  0x040301,0x050301,0x060301,
  0x050401,0x060401,
  0x060501,
  0x040302,0x050302,0x060302,
  0x050402,0x060402,
  0x060502,
  0x050403,0x060403,
  0x060503,
  0x060504};

__device__ __forceinline__ int pos2(int a, int b) {
  return a * 6 - (a * (a - 1)) / 2 + (b - a - 1);
}

__device__ __forceinline__ void nts4(float* p, float4v v) {
  __builtin_nontemporal_store(v, reinterpret_cast<float4v*>(p));
}
__device__ __forceinline__ void nts2(float* p, float2v v) {
  __builtin_nontemporal_store(v, reinterpret_cast<float2v*>(p));
}
__device__ __forceinline__ void nts1(float* p, float v) {
  __builtin_nontemporal_store(v, p);
}

__global__ __launch_bounds__(BLK, 6)   // cap VGPR at 85 -> 6 waves/SIMD
void dform_kernel(const float* __restrict__ x,
                  const float* __restrict__ W1,
                  const float* __restrict__ W2,
                  float* __restrict__ out, int B)
{
  __shared__ float    sW1[DIM][HD + 1];   // [j][h], pad 33 -> conflict-free h0 reads
  __shared__ float    sW2[HD * P2];       // raw W2
  __shared__ _Float16 Mh[NT * 16 * MSTR]; // M col-major, padded rows
  __shared__ float    xs[WPB][WSLAB];     // wave-private x slabs

  const int tid  = threadIdx.x;
  const int lane = tid & 63;
  const int wid  = tid >> 6;
  const int lrow = lane & 15;   // out row within tile
  const int lgrp = lane >> 4;   // k-group / out col group
  const int h0   = lgrp * 8;

  // --- stage raw W1, W2 into LDS (coalesced global reads) ---
  for (int idx = tid; idx < DIM * HD; idx += BLK) sW1[idx / HD][idx % HD] = W1[idx];
  for (int idx = tid; idx < HD * P2; idx += BLK) sW2[idx] = W2[idx];

  // --- wave-private x slab (1 coalesced dwordx4 per lane) ---
  const int gw = blockIdx.x * WPB + wid;          // global wave id
  const int tb = gw * TPW;                        // first tile of this wave
  const long long xbase = (long long)gw * WSLAB;
  float* xw = &xs[wid][0];
  if (xbase + WSLAB <= (long long)B * DIM) {
    const float4v* src = reinterpret_cast<const float4v*>(x + xbase);
    float4v* dst = reinterpret_cast<float4v*>(xw);
    if (lane < WSLAB / 4) dst[lane] = src[lane];  // 56 lanes
  } else {
    for (int i = lane; i < WSLAB; i += 64) {
      long long g = xbase + i;
      xw[i] = (g < (long long)B * DIM) ? x[g] : 0.f;
    }
  }

  __syncthreads();

  // --- build M in LDS from LDS-resident W1/W2 (no scattered VMEM) ---
  for (int idx = tid; idx < NT * 16 * HD; idx += BLK) {
    int col = idx >> 5, h = idx & (HD - 1);
    float val = 0.f;
    if (col < P3) {
      unsigned tr = TRIP[col];
      int i = tr & 255, j = (tr >> 8) & 255, k = (tr >> 16) & 255;
      val = sW1[i][h] * sW2[h * P2 + pos2(j, k)]
          - sW1[j][h] * sW2[h * P2 + pos2(i, k)]
          + sW1[k][h] * sW2[h * P2 + pos2(i, j)];
    }
    Mh[col * MSTR + h] = (_Float16)val;
  }
  __syncthreads();

  // --- x rows for this wave's tiles (conflict-free: 7*lrow mod 32 distinct) ---
  float xr[TPW][DIM];
  #pragma unroll
  for (int i = 0; i < TPW; ++i)
    #pragma unroll
    for (int j = 0; j < DIM; ++j)
      xr[i][j] = xw[(i * 16 + lrow) * DIM + j];

  // --- cos phase: W1 from LDS (broadcast, conflict-free), small live set ---
  half8v cf[TPW];
  #pragma unroll
  for (int e = 0; e < 8; ++e) {
    float w[DIM];
    #pragma unroll
    for (int j = 0; j < DIM; ++j) w[j] = sW1[j][h0 + e];
    #pragma unroll
    for (int i = 0; i < TPW; ++i) {
      float tv = 0.f;
      #pragma unroll
      for (int j = 0; j < DIM; ++j) tv = fmaf(xr[i][j], w[j], tv);
      cf[i][e] = (_Float16)__cosf(tv);
    }
  }

  // --- M fragments (b128, padded stride -> ~2-way max) ---
  half8v mfrag[NT];
  #pragma unroll
  for (int c = 0; c < NT; ++c)
    mfrag[c] = *reinterpret_cast<const half8v*>(&Mh[(c * 16 + lrow) * MSTR + h0]);

  // --- MFMA + nontemporal stores ---
  #pragma unroll
  for (int i = 0; i < TPW; ++i) {
    const int t = tb + i;
    if (t * 16 >= B) break;

    float4v acc[NT];
    #pragma unroll
    for (int c = 0; c < NT; ++c) {
      acc[c] = (float4v){0.f, 0.f, 0.f, 0.f};
      acc[c] = __builtin_amdgcn_mfma_f32_16x16x32_f16(mfrag[c], cf[i], acc[c], 0, 0, 0);
    }

    const int row = t * 16 + lrow;
    if (row < B) {
      float* op = out + (long long)row * P3;
      const int cb = lgrp * 4;
      nts4(op + cb,      acc[0]);
      nts4(op + 16 + cb, acc[1]);
      if (lgrp == 0) {                       // cols 32..34 (35+ pad)
        nts2(op + 32, (float2v){acc[2][0], acc[2][1]});
        nts1(op + 34, acc[2][2]);
      }
    }
  }
}

extern "C" void kernel_launch(void* const* d_in, const int* in_sizes, int n_in,
                              void* d_out, int out_size, void* d_ws, size_t ws_size,
                              hipStream_t stream) {
  const float* x  = (const float*)d_in[0];
  const float* W1 = (const float*)d_in[1];
  const float* W2 = (const float*)d_in[2];
  float* out = (float*)d_out;
  const int B = in_sizes[0] / DIM;
  const int ntiles = (B + 15) / 16;
  const int waves  = (ntiles + TPW - 1) / TPW;
  const int grid   = (waves + WPB - 1) / WPB;  // 2048 for B=262144
  hipLaunchKernelGGL(dform_kernel, dim3(grid), dim3(BLK), 0, stream,
                     x, W1, W2, out, B);
}

// Round 10
// 18.006 us; speedup vs baseline: 1.7400x; 1.7400x over previous
//
#include <hip/hip_runtime.h>

#define DIM 7
#define HD  32   // hidden width
#define P2  21   // C(7,2)
#define P3  35   // C(7,3)
#define BLK 512
#define NT  3    // 16-wide output-col tiles (48 cols, 35 used)
#define TPW 4    // 16-row tiles per wave
#define WPB (BLK / 64)           // 8 waves per block
#define WSLAB (TPW * 16 * DIM)   // 448 floats of x per wave

typedef __attribute__((ext_vector_type(8))) _Float16 half8v;  // MFMA A/B operand
typedef __attribute__((ext_vector_type(4))) float  float4v;   // MFMA accumulator

// packed (i | j<<8 | k<<16) for lexicographic triples of 7
static __device__ const unsigned TRIP[P3] = {
  0x020100,0x030100,0x040100,0x050100,0x060100,
  0x030200,0x040200,0x050200,0x060200,
  0x040300,0x050300,0x060300,
  0x050400,0x060400,
  0x060500,
  0x030201,0x040201,0x050201,0x060201,
  0x040301,0x050301,0x060301,
  0x050401,0x060401,
  0x060501,
  0x040302,0x050302,0x060302,
  0x050402,0x060402,
  0x060502,
  0x050403,0x060403,
  0x060503,
  0x060504};

__device__ __forceinline__ int pos2(int a, int b) {
  return a * 6 - (a * (a - 1)) / 2 + (b - a - 1);
}

__global__ __launch_bounds__(BLK)
void dform_kernel(const float* __restrict__ x,
                  const float* __restrict__ W1,
                  const float* __restrict__ W2,
                  float* __restrict__ out, int B)
{
  __shared__ float    sW1[DIM][HD + 1];   // padded: cos-phase reads broadcast, conflict-free
  __shared__ float    sW2[HD * P2];
  __shared__ _Float16 Mh[NT * 16 * HD];   // M col-major: Mh[col*HD + h]
  __shared__ float    xs[WPB][WSLAB];     // wave-private x slabs (14 KB)

  const int tid  = threadIdx.x;
  const int lane = tid & 63;
  const int wid  = tid >> 6;
  const int lrow = lane & 15;   // out row within tile
  const int lgrp = lane >> 4;   // k-group / out col group
  const int h0   = lgrp * 8;

  // --- (1) wave-private x slab FIRST: HBM latency hides under prologue ---
  const int gw = blockIdx.x * WPB + wid;          // global wave id
  const int tb = gw * TPW;                        // first tile of this wave
  const long long xbase = (long long)gw * WSLAB;  // 1792B-aligned
  float* xw = &xs[wid][0];
  if (xbase + WSLAB <= (long long)B * DIM) {
    const float4* src = reinterpret_cast<const float4*>(x + xbase);
    float4* dst = reinterpret_cast<float4*>(xw);
    dst[lane] = src[lane];
    if (lane < WSLAB / 4 - 64) dst[lane + 64] = src[lane + 64];  // lanes 0..47
  } else {
    for (int i = lane; i < WSLAB; i += 64) {
      long long g = xbase + i;
      xw[i] = (g < (long long)B * DIM) ? x[g] : 0.f;
    }
  }

  // --- (2) stage raw W1/W2 coalesced ---
  for (int idx = tid; idx < DIM * HD; idx += BLK) sW1[idx / HD][idx % HD] = W1[idx];
  for (int idx = tid; idx < HD * P2; idx += BLK) sW2[idx] = W2[idx];
  __syncthreads();

  // --- (3) build M from LDS-resident W1/W2 (3 elements per thread) ---
  for (int idx = tid; idx < NT * 16 * HD; idx += BLK) {
    int col = idx >> 5, h = idx & (HD - 1);
    float val = 0.f;
    if (col < P3) {
      unsigned tr = TRIP[col];
      int i = tr & 255, j = (tr >> 8) & 255, k = (tr >> 16) & 255;
      val = sW1[i][h] * sW2[h * P2 + pos2(j, k)]
          - sW1[j][h] * sW2[h * P2 + pos2(i, k)]
          + sW1[k][h] * sW2[h * P2 + pos2(i, j)];
    }
    Mh[idx] = (_Float16)val;
  }
  __syncthreads();

  // --- (4) x rows into registers (bank 7*lrow%32: 16 distinct, 4-lane bcast) ---
  float xr[TPW][DIM];
  #pragma unroll
  for (int i = 0; i < TPW; ++i)
    #pragma unroll
    for (int j = 0; j < DIM; ++j)
      xr[i][j] = xw[(i * 16 + lrow) * DIM + j];

  // --- (5) cos phase: W1 via LDS broadcast (4 addrs/read, same-addr bcast) ---
  half8v cf[TPW];
  #pragma unroll
  for (int e = 0; e < 8; ++e) {
    float w[DIM];
    #pragma unroll
    for (int j = 0; j < DIM; ++j) w[j] = sW1[j][h0 + e];
    #pragma unroll
    for (int i = 0; i < TPW; ++i) {
      float tv = 0.f;
      #pragma unroll
      for (int j = 0; j < DIM; ++j) tv = fmaf(xr[i][j], w[j], tv);
      cf[i][e] = (_Float16)__cosf(tv);
    }
  }

  // --- (6) M fragments (b128; once per wave) ---
  half8v mfrag[NT];
  #pragma unroll
  for (int c = 0; c < NT; ++c)
    mfrag[c] = *reinterpret_cast<const half8v*>(&Mh[(c * 16 + lrow) * HD + h0]);

  // --- (7) MFMA + direct dwordx4 stores (r7-proven epilogue) ---
  #pragma unroll
  for (int i = 0; i < TPW; ++i) {
    const int t = tb + i;
    if (t * 16 >= B) break;

    float4v acc[NT];
    #pragma unroll
    for (int c = 0; c < NT; ++c) {
      acc[c] = (float4v){0.f, 0.f, 0.f, 0.f};
      acc[c] = __builtin_amdgcn_mfma_f32_16x16x32_f16(mfrag[c], cf[i], acc[c], 0, 0, 0);
    }

    const int row = t * 16 + lrow;
    if (row < B) {
      float* op = out + (long long)row * P3;
      const int cb = lgrp * 4;
      *reinterpret_cast<float4*>(op + cb) =
          make_float4(acc[0][0], acc[0][1], acc[0][2], acc[0][3]);
      *reinterpret_cast<float4*>(op + 16 + cb) =
          make_float4(acc[1][0], acc[1][1], acc[1][2], acc[1][3]);
      if (lgrp == 0) {   // cols 32..34 (35+ pad)
        *reinterpret_cast<float2*>(op + 32) = make_float2(acc[2][0], acc[2][1]);
        op[34] = acc[2][2];
      }
    }
  }
}

extern "C" void kernel_launch(void* const* d_in, const int* in_sizes, int n_in,
                              void* d_out, int out_size, void* d_ws, size_t ws_size,
                              hipStream_t stream) {
  const float* x  = (const float*)d_in[0];
  const float* W1 = (const float*)d_in[1];
  const float* W2 = (const float*)d_in[2];
  float* out = (float*)d_out;
  const int B = in_sizes[0] / DIM;
  const int ntiles = (B + 15) / 16;
  const int waves  = (ntiles + TPW - 1) / TPW;
  const int grid   = (waves + WPB - 1) / WPB;   // 512 for B=262144
  hipLaunchKernelGGL(dform_kernel, dim3(grid), dim3(BLK), 0, stream,
                     x, W1, W2, out, B);
}